// Round 2
// baseline (7481.751 us; speedup 1.0000x reference)
//
#include <hip/hip_runtime.h>
#include <hip/hip_bf16.h>
#include <hip/hip_cooperative_groups.h>

namespace cg = cooperative_groups;

#define T_STEPS 512
#define BSZ 64
#define DIM 512
#define HID 512
#define NWG 64
#define NTHR 256

typedef __attribute__((ext_vector_type(16))) float f32x16;
typedef __attribute__((ext_vector_type(8))) short short8;

__device__ __forceinline__ short f2bf(float f) {
  __hip_bfloat16 h = __float2bfloat16(f);   // RNE; compiler emits packed cvt
  return *reinterpret_cast<short*>(&h);
}

__global__ __launch_bounds__(NTHR, 1) void lstm_kernel(
    const float* __restrict__ X, const float* __restrict__ W,
    const float* __restrict__ Bv, float* __restrict__ Out,
    unsigned int* __restrict__ flags)
{
  extern __shared__ char lds[];
  char*  Wl  = lds;                    // 64 KiB: B-frags, addr = kk*1024 + half*512 + col*16
  char*  Red = lds + 65536;            // 2 x 4 KiB K-split reduction

  const int tid  = threadIdx.x;
  const int wg   = blockIdx.x;         // 0..63 -> h cols [8wg, 8wg+8)
  const int lane = tid & 63;
  const int wv   = tid >> 6;           // 0..3
  const int m    = wv & 1;             // M-tile: rows [32m, 32m+32)
  const bool is_h = (wv >= 2);

  // ---- one-time: W slice -> LDS as 32x32x16 B-fragments (bf16) ----
  // packed col c = g*8 + hl  ->  global col g*512 + wg*8 + hl
  {
    const int c  = tid & 31;
    const int gc = (c >> 3) * 512 + wg * 8 + (c & 7);
    for (int kk = tid >> 5; kk < 64; kk += 8) {
      #pragma unroll
      for (int half = 0; half < 2; ++half) {
        short8 v;
        #pragma unroll
        for (int j = 0; j < 8; ++j)
          v[j] = f2bf(W[(size_t)(kk * 16 + half * 8 + j) * 2048 + gc]);
        *(short8*)(Wl + kk * 1024 + half * 512 + c * 16) = v;
      }
    }
  }

  // ---- fragment addressing ----
  const int arow  = m * 32 + (lane & 31);      // A row (batch)
  const int aoff  = (lane >> 5) * 8;           // k offset within K=16 frag
  const int baddr = (lane >> 5) * 512 + (lane & 31) * 16;

  // GEMM over K=512: A from global fp32 (cvt to bf16), B from Wl at kk-base kb
  auto gemm = [&](const float* __restrict__ src, int kb) -> f32x16 {
    const float* ap = src + (size_t)arow * 512 + aoff;
    f32x16 acc0, acc1;
    #pragma unroll
    for (int i = 0; i < 16; ++i) { acc0[i] = 0.f; acc1[i] = 0.f; }
    #pragma unroll 2
    for (int kk = 0; kk < 32; kk += 2) {
      const float4 u0 = *(const float4*)(ap + kk * 16);
      const float4 u1 = *(const float4*)(ap + kk * 16 + 4);
      const float4 w0 = *(const float4*)(ap + kk * 16 + 16);
      const float4 w1 = *(const float4*)(ap + kk * 16 + 20);
      short8 a0, a1;
      a0[0] = f2bf(u0.x); a0[1] = f2bf(u0.y); a0[2] = f2bf(u0.z); a0[3] = f2bf(u0.w);
      a0[4] = f2bf(u1.x); a0[5] = f2bf(u1.y); a0[6] = f2bf(u1.z); a0[7] = f2bf(u1.w);
      a1[0] = f2bf(w0.x); a1[1] = f2bf(w0.y); a1[2] = f2bf(w0.z); a1[3] = f2bf(w0.w);
      a1[4] = f2bf(w1.x); a1[5] = f2bf(w1.y); a1[6] = f2bf(w1.z); a1[7] = f2bf(w1.w);
      const short8 b0 = *(const short8*)(Wl + (kb + kk) * 1024 + baddr);
      const short8 b1 = *(const short8*)(Wl + (kb + kk + 1) * 1024 + baddr);
      acc0 = __builtin_amdgcn_mfma_f32_32x32x16_bf16(a0, b0, acc0, 0, 0, 0);
      acc1 = __builtin_amdgcn_mfma_f32_32x32x16_bf16(a1, b1, acc1, 0, 0, 0);
    }
    #pragma unroll
    for (int i = 0; i < 16; ++i) acc0[i] += acc1[i];
    return acc0;
  };

  // ---- epilogue constants: lane col c = g*8 + hl ----
  const int   c    = lane & 31;
  const int   g    = c >> 3;                   // 0=f 1=i 2=g 3=o
  const int   hc   = wg * 8 + (c & 7);         // global h column
  const float bias = Bv[g * 512 + hc];

  float cst[16];
  #pragma unroll
  for (int r = 0; r < 16; ++r) cst[r] = 0.f;

  // ---- bootstrap (robust across graph replays) ----
  if (tid == 0)
    __hip_atomic_store(&flags[wg * 32], 0u, __ATOMIC_RELAXED, __HIP_MEMORY_SCOPE_AGENT);
  cg::this_grid().sync();

  for (int t = 0; t < T_STEPS; ++t) {
    // -------- phase 1: x-waves GEMM(x_t) || h-waves wait for h_{t-1} --------
    if (!is_h) {
      f32x16 acc = gemm(X + (size_t)t * (BSZ * DIM), 0);
      #pragma unroll
      for (int q = 0; q < 4; ++q) {
        float4 v = make_float4(acc[4*q], acc[4*q+1], acc[4*q+2], acc[4*q+3]);
        *(float4*)(Red + m * 4096 + q * 1024 + lane * 16) = v;
      }
    } else if (t > 0) {
      const unsigned want = (unsigned)t;
      while (__hip_atomic_load(&flags[lane * 32], __ATOMIC_RELAXED,
                               __HIP_MEMORY_SCOPE_AGENT) < want) {}
      if (tid == 128) __threadfence();   // buffer_inv: no stale L2 lines for h reads
    }
    __syncthreads();   // B1

    // -------- phase 2: h-waves GEMM(h_{t-1}) + reduce + pointwise --------
    if (is_h) {
      f32x16 acc;
      if (t > 0) {
        acc = gemm(Out + (size_t)(t - 1) * (BSZ * HID), 32);
      } else {
        #pragma unroll
        for (int i = 0; i < 16; ++i) acc[i] = 0.f;
      }
      #pragma unroll
      for (int q = 0; q < 4; ++q) {
        float4 v = *(const float4*)(Red + m * 4096 + q * 1024 + lane * 16);
        acc[4*q+0] += v.x; acc[4*q+1] += v.y; acc[4*q+2] += v.z; acc[4*q+3] += v.w;
      }
      #pragma unroll
      for (int r = 0; r < 16; ++r) {
        const float pre = acc[r] + bias;
        const float e   = __expf((g == 2) ? -2.f * pre : -pre);
        const float act = (g == 2) ? (2.f / (1.f + e) - 1.f) : (1.f / (1.f + e));
        const float vi  = __shfl_xor(act, 8);    // f-lane <- i act
        const float vg  = __shfl_xor(act, 16);   // f-lane <- g act
        const float cn  = act * cst[r] + vi * vg;  // valid on f-lanes
        if (g == 0) cst[r] = cn;
        const float e2  = __expf(-2.f * cn);
        float tn = 2.f / (1.f + e2) - 1.f;
        tn = __shfl_xor(tn, 24);                 // o-lane <- tanh(c_new)
        const int row = m * 32 + (r & 3) + 8 * (r >> 2) + 4 * (lane >> 5);
        if (g == 3) {
          const float h = act * tn;
          __hip_atomic_store(Out + ((size_t)t * BSZ + row) * HID + hc, h,
                             __ATOMIC_RELAXED, __HIP_MEMORY_SCOPE_AGENT);
          if (t == T_STEPS - 1)
            Out[(size_t)T_STEPS * BSZ * HID + (size_t)row * HID + hc] = h;      // hx
        }
        if (g == 0 && t == T_STEPS - 1)
          Out[(size_t)T_STEPS * BSZ * HID + BSZ * HID + (size_t)row * HID + hc] = cn; // cx
      }
    }
    __syncthreads();   // B2: drains h stores (vmcnt) before publish

    if (tid == 128)
      __hip_atomic_store(&flags[wg * 32], (unsigned)(t + 1),
                         __ATOMIC_RELEASE, __HIP_MEMORY_SCOPE_AGENT);
  }
}

extern "C" void kernel_launch(void* const* d_in, const int* in_sizes, int n_in,
                              void* d_out, int out_size, void* d_ws, size_t ws_size,
                              hipStream_t stream) {
  const float* X  = (const float*)d_in[0];
  const float* W  = (const float*)d_in[1];
  const float* Bv = (const float*)d_in[2];
  float* Out = (float*)d_out;
  unsigned int* flags = (unsigned int*)d_ws;

  hipFuncSetAttribute((const void*)lstm_kernel,
                      hipFuncAttributeMaxDynamicSharedMemorySize, 73728);

  void* args[5];
  args[0] = (void*)&X;
  args[1] = (void*)&W;
  args[2] = (void*)&Bv;
  args[3] = (void*)&Out;
  args[4] = (void*)&flags;
  hipLaunchCooperativeKernel((const void*)lstm_kernel, dim3(NWG), dim3(NTHR),
                             args, 73728, stream);
}